// Round 1
// baseline (346.356 us; speedup 1.0000x reference)
//
#include <hip/hip_runtime.h>
#include <hip/hip_bf16.h>

#define NGRAPH  64
#define TOPO_D  16
#define NBLK    512     // binning blocks (pass A); E=1.6M -> 3125 edges/block
#define MAXB    512     // LDS cap for bucket arrays (nb2 = ceil(N/256) = 391)
#define GROWS   8       // rows per wave in the register GEMM

typedef float v2f __attribute__((ext_vector_type(2)));

// exact RNE float -> bf16 pack
static __device__ __forceinline__ unsigned f2bf(float f) {
    unsigned u = __float_as_uint(f);
    return (u + 0x7FFFu + ((u >> 16) & 1u)) >> 16;
}
static __device__ __forceinline__ float bf_lo(unsigned u) { return __uint_as_float(u << 16); }
static __device__ __forceinline__ float bf_hi(unsigned u) { return __uint_as_float(u & 0xFFFF0000u); }

// ---- gemm1 body: fp32 rows x W1 -> bf16 (unscaled) -------------------------------------------
static __device__ __forceinline__ void gemm_rows_bf(
        const float* __restrict__ X, const float* Wreg,
        unsigned short* __restrict__ Abf, int row0, int N, int lane) {
    #pragma unroll
    for (int j = 0; j < GROWS; ++j) {
        int row = row0 + j;
        if (row >= N) return;
        const float* xr = X + (size_t)row * 64;
        float acc = 0.0f;
        #pragma unroll
        for (int k = 0; k < 64; ++k) acc = fmaf(xr[k], Wreg[k], acc);
        Abf[(size_t)row * 64 + lane] = (unsigned short)f2bf(acc);
    }
}

// ---- pass A1 hybrid: blocks [0,Gg) = gemm1 (bf16); [Gg,Gg+NBLK) = bucket histogram -----------
__global__ __launch_bounds__(256) void hybrid_gemm_hist_kernel(
        const float* __restrict__ X, const float* __restrict__ W,
        unsigned short* __restrict__ Abf,
        const int* __restrict__ dst, int* __restrict__ bhist,
        int N, int E, int Gg, int nb2, int CE) {
    __shared__ int hist[MAXB];
    int t = threadIdx.x;
    if ((int)blockIdx.x < Gg) {
        int lane = t & 63;
        float Wreg[64];
        #pragma unroll
        for (int k = 0; k < 64; ++k) Wreg[k] = W[k * 64 + lane];
        int wave = __builtin_amdgcn_readfirstlane(blockIdx.x * 4 + (t >> 6));
        gemm_rows_bf(X, Wreg, Abf, wave * GROWS, N, lane);
    } else {
        int blk = blockIdx.x - Gg;               // 0..NBLK-1
        for (int i = t; i < nb2; i += 256) hist[i] = 0;
        __syncthreads();
        int e0 = blk * CE, e1 = min(e0 + CE, E);
        for (int e = e0 + t; e < e1; e += 256) atomicAdd(&hist[dst[e] >> 8], 1);
        __syncthreads();
        for (int i = t; i < nb2; i += 256) bhist[blk * nb2 + i] = hist[i];
    }
}

// ---- pass A2a: exclusive scan down each bucket column of bhist (nblk=512 fixed) --------------
__global__ __launch_bounds__(256) void scan_cols_kernel(
        int* __restrict__ bhist, int* __restrict__ ctot, int nb2) {
    __shared__ int sd[256];
    int c = blockIdx.x;
    int t = threadIdx.x;
    int v0 = bhist[t * nb2 + c];
    int v1 = bhist[(t + 256) * nb2 + c];
    int tsum = v0 + v1;
    sd[t] = tsum; __syncthreads();
    for (int off = 1; off < 256; off <<= 1) {
        int u = (t >= off) ? sd[t - off] : 0;
        __syncthreads();
        sd[t] += u;
        __syncthreads();
    }
    int excl = sd[t] - tsum;
    bhist[t * nb2 + c] = excl;
    bhist[(t + 256) * nb2 + c] = excl + v0;
    if (t == 255) ctot[c] = sd[255];
}

// ---- pass A2b merged: block 0 = scan of bucket totals -> cbase; block 1 = gstart -------------
__global__ void scan_gstart_kernel(const int* __restrict__ ctot, int* __restrict__ cbase,
                                   const int* __restrict__ batch, int* __restrict__ gstart,
                                   int nb2, int N) {
    if (blockIdx.x == 0) {
        int lane = threadIdx.x;
        if (lane >= 64) return;
        int base = lane * 8;
        int vals[8];
        int s = 0;
        #pragma unroll
        for (int k = 0; k < 8; ++k) {
            int i = base + k;
            int v = (i < nb2) ? ctot[i] : 0;
            vals[k] = s; s += v;
        }
        int inc = s;
        for (int off = 1; off < 64; off <<= 1) {
            int u = __shfl_up(inc, off, 64);
            if (lane >= off) inc += u;
        }
        int lexcl = inc - s;
        #pragma unroll
        for (int k = 0; k < 8; ++k) {
            int i = base + k;
            if (i <= nb2) cbase[i] = lexcl + vals[k];
        }
    } else {
        int g = threadIdx.x;
        if (g > NGRAPH) return;
        int lo = 0, hi = N;
        while (lo < hi) {
            int mid = (lo + hi) >> 1;
            if (batch[mid] < g) lo = mid + 1; else hi = mid;
        }
        gstart[g] = lo;
    }
}

// ---- pass A3: scatter edges into dst-buckets, packed (src<<8 | dst&255) ----------------------
__global__ __launch_bounds__(256) void scatter_sorted_kernel(
        const int* __restrict__ src, const int* __restrict__ dst,
        const int* __restrict__ bhist, const int* __restrict__ cbase,
        unsigned* __restrict__ ebuf, int E, int nb2, int CE) {
    __shared__ int cur[MAXB];
    int blk = blockIdx.x, t = threadIdx.x;
    for (int i = t; i < nb2; i += 256) cur[i] = bhist[blk * nb2 + i] + cbase[i];
    __syncthreads();
    int e0 = blk * CE, e1 = min(e0 + CE, E);
    for (int e = e0 + t; e < e1; e += 256) {
        int d = dst[e];
        int pos = atomicAdd(&cur[d >> 8], 1);
        ebuf[pos] = ((unsigned)src[e] << 8) | (unsigned)(d & 255);
    }
}

// ---- pass B: per bucket: CSR col/rowptr/degi/dis + convert A bf16 -> fp8 (x dis) -------------
__global__ __launch_bounds__(256) void build_csr_kernel(
        const unsigned* __restrict__ ebuf, const int* __restrict__ cbase,
        int* __restrict__ col, int* __restrict__ rowptr,
        int* __restrict__ degi, float* __restrict__ dis,
        const unsigned* __restrict__ Abf32, unsigned* __restrict__ A8, int N) {
    __shared__ int cnt[256];
    __shared__ int loff[256];
    __shared__ float disS[256];
    int b = blockIdx.x, t = threadIdx.x;
    int e0 = cbase[b], e1 = cbase[b + 1];
    cnt[t] = 0; __syncthreads();
    for (int i = e0 + t; i < e1; i += 256) atomicAdd(&cnt[ebuf[i] & 255u], 1);
    __syncthreads();
    int v = cnt[t];
    loff[t] = v; __syncthreads();
    for (int off = 1; off < 256; off <<= 1) {
        int u = (t >= off) ? loff[t - off] : 0;
        __syncthreads();
        loff[t] += u;
        __syncthreads();
    }
    int excl = loff[t] - v;
    int node = b * 256 + t;
    float ds = rsqrtf((float)v + 1.0f);
    disS[t] = ds;
    if (node < N) {
        degi[node]   = v;
        dis[node]    = ds;
        rowptr[node] = e0 + excl;
    }
    __syncthreads();
    cnt[t] = excl;              // reuse as local cursor
    __syncthreads();
    for (int i = e0 + t; i < e1; i += 256) {
        unsigned p = ebuf[i];
        int pos = atomicAdd(&cnt[p & 255u], 1);
        col[e0 + pos] = (int)(p >> 8);
    }
    // convert this bucket's A rows: bf16 * dis -> fp8 (16 dwords/row out)
    int base8 = b * 256 * 16;
    for (int i = t; i < 256 * 16; i += 256) {
        int r = i >> 4;               // row in bucket
        int dwo = i & 15;             // output dword (4 feats)
        int nd = b * 256 + r;
        if (nd < N) {
            float d2 = disS[r];
            unsigned u0 = Abf32[(size_t)nd * 32 + dwo * 2];
            unsigned u1 = Abf32[(size_t)nd * 32 + dwo * 2 + 1];
            int dw = __builtin_amdgcn_cvt_pk_fp8_f32(bf_lo(u0) * d2, bf_hi(u0) * d2, 0, false);
            dw = __builtin_amdgcn_cvt_pk_fp8_f32(bf_lo(u1) * d2, bf_hi(u1) * d2, dw, true);
            A8[base8 + i] = (unsigned)dw;
        }
    }
}

// ---- shared gather core: 8 nodes/wave, feature-sliced, fp8, acc init = self row --------------
static __device__ __forceinline__ void gather_node(
        const unsigned* __restrict__ A8, const int* __restrict__ col,
        int beg, int deg, int node, int f8, float acc[8]) {
    const char* Abase = (const char*)A8 + f8 * 8;
    uint2 an = *(const uint2*)(Abase + ((size_t)node << 6));
    v2f a0 = __builtin_amdgcn_cvt_pk_f32_fp8(an.x, false);
    v2f a1 = __builtin_amdgcn_cvt_pk_f32_fp8(an.x, true);
    v2f a2 = __builtin_amdgcn_cvt_pk_f32_fp8(an.y, false);
    v2f a3 = __builtin_amdgcn_cvt_pk_f32_fp8(an.y, true);
    acc[0] = a0.x; acc[1] = a0.y; acc[2] = a1.x; acc[3] = a1.y;
    acc[4] = a2.x; acc[5] = a2.y; acc[6] = a3.x; acc[7] = a3.y;
    int j = 0;
    for (; j + 4 <= deg; j += 4) {               // 4 gathers in flight per lane
        int s0 = col[beg + j]     << 6;
        int s1 = col[beg + j + 1] << 6;
        int s2 = col[beg + j + 2] << 6;
        int s3 = col[beg + j + 3] << 6;
        uint2 v0 = *(const uint2*)(Abase + s0);
        uint2 v1 = *(const uint2*)(Abase + s1);
        uint2 v2 = *(const uint2*)(Abase + s2);
        uint2 v3 = *(const uint2*)(Abase + s3);
        v2f f0, f1, f2, f3;
        f0 = __builtin_amdgcn_cvt_pk_f32_fp8(v0.x, false); acc[0] += f0.x; acc[1] += f0.y;
        f1 = __builtin_amdgcn_cvt_pk_f32_fp8(v0.x, true);  acc[2] += f1.x; acc[3] += f1.y;
        f2 = __builtin_amdgcn_cvt_pk_f32_fp8(v0.y, false); acc[4] += f2.x; acc[5] += f2.y;
        f3 = __builtin_amdgcn_cvt_pk_f32_fp8(v0.y, true);  acc[6] += f3.x; acc[7] += f3.y;
        f0 = __builtin_amdgcn_cvt_pk_f32_fp8(v1.x, false); acc[0] += f0.x; acc[1] += f0.y;
        f1 = __builtin_amdgcn_cvt_pk_f32_fp8(v1.x, true);  acc[2] += f1.x; acc[3] += f1.y;
        f2 = __builtin_amdgcn_cvt_pk_f32_fp8(v1.y, false); acc[4] += f2.x; acc[5] += f2.y;
        f3 = __builtin_amdgcn_cvt_pk_f32_fp8(v1.y, true);  acc[6] += f3.x; acc[7] += f3.y;
        f0 = __builtin_amdgcn_cvt_pk_f32_fp8(v2.x, false); acc[0] += f0.x; acc[1] += f0.y;
        f1 = __builtin_amdgcn_cvt_pk_f32_fp8(v2.x, true);  acc[2] += f1.x; acc[3] += f1.y;
        f2 = __builtin_amdgcn_cvt_pk_f32_fp8(v2.y, false); acc[4] += f2.x; acc[5] += f2.y;
        f3 = __builtin_amdgcn_cvt_pk_f32_fp8(v2.y, true);  acc[6] += f3.x; acc[7] += f3.y;
        f0 = __builtin_amdgcn_cvt_pk_f32_fp8(v3.x, false); acc[0] += f0.x; acc[1] += f0.y;
        f1 = __builtin_amdgcn_cvt_pk_f32_fp8(v3.x, true);  acc[2] += f1.x; acc[3] += f1.y;
        f2 = __builtin_amdgcn_cvt_pk_f32_fp8(v3.y, false); acc[4] += f2.x; acc[5] += f2.y;
        f3 = __builtin_amdgcn_cvt_pk_f32_fp8(v3.y, true);  acc[6] += f3.x; acc[7] += f3.y;
    }
    for (; j < deg; ++j) {
        int s = col[beg + j] << 6;
        uint2 v = *(const uint2*)(Abase + s);
        v2f f0 = __builtin_amdgcn_cvt_pk_f32_fp8(v.x, false);
        v2f f1 = __builtin_amdgcn_cvt_pk_f32_fp8(v.x, true);
        v2f f2 = __builtin_amdgcn_cvt_pk_f32_fp8(v.y, false);
        v2f f3 = __builtin_amdgcn_cvt_pk_f32_fp8(v.y, true);
        acc[0] += f0.x; acc[1] += f0.y; acc[2] += f1.x; acc[3] += f1.y;
        acc[4] += f2.x; acc[5] += f2.y; acc[6] += f3.x; acc[7] += f3.y;
    }
}

// ---- fused layer1 pull + GEMM2: gather A8a -> h1 (bf16, wave-local LDS) -> xW2 -> fp8 A8b ----
// Each wave's 8x64 h1 tile round-trips through 1KB of its own LDS; no global Bbf.
__global__ __launch_bounds__(256) void pull1_gemm_kernel(
        const unsigned* __restrict__ A8a, const int* __restrict__ rowptr,
        const int* __restrict__ degi, const float* __restrict__ dis,
        const float* __restrict__ bias, const int* __restrict__ col,
        const float* __restrict__ W2, unsigned* __restrict__ A8b, int N) {
    __shared__ __align__(16) unsigned hl[4][8][32];   // [wave][row][32 dwords of bf16x2]
    int w = threadIdx.x >> 6;
    int waveg = (blockIdx.x * blockDim.x + threadIdx.x) >> 6;
    int lane = threadIdx.x & 63;
    int i = lane >> 3;
    int f8 = lane & 7;
    int node = waveg * 8 + i;
    bool valid = node < N;
    if (!valid) node = N - 1;
    int deg = degi[node];
    int beg = rowptr[node];
    float acc[8];
    gather_node(A8a, col, beg, deg, node, f8, acc);
    float d = dis[node];
    float4 b0 = ((const float4*)bias)[f8 * 2];
    float4 b1 = ((const float4*)bias)[f8 * 2 + 1];
    float r0 = fmaxf(d * acc[0] + b0.x, 0.f);
    float r1 = fmaxf(d * acc[1] + b0.y, 0.f);
    float r2 = fmaxf(d * acc[2] + b0.z, 0.f);
    float r3 = fmaxf(d * acc[3] + b0.w, 0.f);
    float r4 = fmaxf(d * acc[4] + b1.x, 0.f);
    float r5 = fmaxf(d * acc[5] + b1.y, 0.f);
    float r6 = fmaxf(d * acc[6] + b1.z, 0.f);
    float r7 = fmaxf(d * acc[7] + b1.w, 0.f);
    uint4 o;
    o.x = f2bf(r0) | (f2bf(r1) << 16);
    o.y = f2bf(r2) | (f2bf(r3) << 16);
    o.z = f2bf(r4) | (f2bf(r5) << 16);
    o.w = f2bf(r6) | (f2bf(r7) << 16);
    *(uint4*)&hl[w][i][f8 * 4] = o;
    __syncthreads();        // also fences W2 loads below from hoisting over the gather
    // gemm phase: this wave consumes exactly the 8 rows it produced
    float Wreg[64];
    #pragma unroll
    for (int k = 0; k < 64; ++k) Wreg[k] = W2[k * 64 + lane];
    int row0 = __builtin_amdgcn_readfirstlane(waveg) * 8;
    #pragma unroll
    for (int j = 0; j < 8; ++j) {
        int row = row0 + j;
        if (row >= N) break;
        const uint4* xr4 = (const uint4*)&hl[w][j][0];   // wave-uniform -> ds_read broadcast
        float a2 = 0.0f;
        #pragma unroll
        for (int k4 = 0; k4 < 8; ++k4) {
            uint4 u4 = xr4[k4];
            a2 = fmaf(bf_lo(u4.x), Wreg[8 * k4 + 0], a2);
            a2 = fmaf(bf_hi(u4.x), Wreg[8 * k4 + 1], a2);
            a2 = fmaf(bf_lo(u4.y), Wreg[8 * k4 + 2], a2);
            a2 = fmaf(bf_hi(u4.y), Wreg[8 * k4 + 3], a2);
            a2 = fmaf(bf_lo(u4.z), Wreg[8 * k4 + 4], a2);
            a2 = fmaf(bf_hi(u4.z), Wreg[8 * k4 + 5], a2);
            a2 = fmaf(bf_lo(u4.w), Wreg[8 * k4 + 6], a2);
            a2 = fmaf(bf_hi(u4.w), Wreg[8 * k4 + 7], a2);
        }
        a2 *= dis[row];
        // cross-lane pack: features 4k..4k+3 -> one dword, stored by lane 4k
        float nb1 = __shfl_xor(a2, 1, 64);
        float lo = (lane & 1) ? nb1 : a2;
        float hi = (lane & 1) ? a2 : nb1;
        int pk = __builtin_amdgcn_cvt_pk_fp8_f32(lo, hi, 0, false);
        int pk2 = __shfl_xor(pk, 2, 64);
        unsigned dw = (lane & 2) ? (((unsigned)pk2 & 0xFFFFu) | ((unsigned)pk << 16))
                                 : (((unsigned)pk & 0xFFFFu) | ((unsigned)pk2 << 16));
        if ((lane & 3) == 0) A8b[(size_t)row * 16 + (lane >> 2)] = dw;
    }
}

// ---- fused layer2 pull + mean-pool: gather A8b -> h2 -> wave butterfly -> atomics to gsum ----
__global__ __launch_bounds__(256) void pull2_pool_kernel(
        const unsigned* __restrict__ A8b, const int* __restrict__ rowptr,
        const int* __restrict__ degi, const float* __restrict__ dis,
        const float* __restrict__ bias, const int* __restrict__ col,
        const int* __restrict__ batch, float* __restrict__ gsum, int N) {
    int waveg = (blockIdx.x * blockDim.x + threadIdx.x) >> 6;
    int lane = threadIdx.x & 63;
    int i = lane >> 3;
    int f8 = lane & 7;
    int node = waveg * 8 + i;
    bool valid = node < N;
    if (!valid) node = N - 1;
    int deg = degi[node];
    int beg = rowptr[node];
    float acc[8];
    gather_node(A8b, col, beg, deg, node, f8, acc);
    float d = dis[node];
    float4 b0 = ((const float4*)bias)[f8 * 2];
    float4 b1 = ((const float4*)bias)[f8 * 2 + 1];
    float r[8];
    r[0] = fmaxf(d * acc[0] + b0.x, 0.f);
    r[1] = fmaxf(d * acc[1] + b0.y, 0.f);
    r[2] = fmaxf(d * acc[2] + b0.z, 0.f);
    r[3] = fmaxf(d * acc[3] + b0.w, 0.f);
    r[4] = fmaxf(d * acc[4] + b1.x, 0.f);
    r[5] = fmaxf(d * acc[5] + b1.y, 0.f);
    r[6] = fmaxf(d * acc[6] + b1.z, 0.f);
    r[7] = fmaxf(d * acc[7] + b1.w, 0.f);
    if (!valid) {
        #pragma unroll
        for (int j = 0; j < 8; ++j) r[j] = 0.f;
    }
    int g = batch[node];
    int gFirst = __shfl(g, 0, 64);
    int gLast  = __shfl(g, 63, 64);
    if (gFirst == gLast) {
        // all 8 nodes in this wave belong to one graph (common: batch is sorted)
        #pragma unroll
        for (int j = 0; j < 8; ++j) {
            r[j] += __shfl_xor(r[j], 8, 64);
            r[j] += __shfl_xor(r[j], 16, 64);
            r[j] += __shfl_xor(r[j], 32, 64);
        }
        if (i == 0) {
            #pragma unroll
            for (int j = 0; j < 8; ++j)
                unsafeAtomicAdd(&gsum[gFirst * 64 + f8 * 8 + j], r[j]);
        }
    } else {
        // graph boundary inside the wave (rare: ~63 waves of 12500)
        #pragma unroll
        for (int j = 0; j < 8; ++j)
            unsafeAtomicAdd(&gsum[g * 64 + f8 * 8 + j], r[j]);
    }
}

// ---- head: counts derived from gstart --------------------------------------------------------
__global__ __launch_bounds__(256) void head_kernel(
        const float* __restrict__ gsum, const int* __restrict__ gstart,
        const float* __restrict__ topo, const float* __restrict__ Wlin,
        const float* __restrict__ blin, float* __restrict__ out) {
    int t = threadIdx.x;              // 256 = 64 graphs x 4 classes
    int g = t >> 2;
    int c = t & 3;
    float cntf = (float)(gstart[g + 1] - gstart[g]);
    float inv = 1.0f / fmaxf(cntf, 1.0f);
    float v = blin[c];
    #pragma unroll
    for (int f = 0; f < 64; ++f) v += gsum[g * 64 + f] * inv * Wlin[f * 4 + c];
    #pragma unroll
    for (int t2 = 0; t2 < TOPO_D; ++t2) v += topo[g * TOPO_D + t2] * Wlin[(64 + t2) * 4 + c];
    out[g * 4 + c] = v;
}

extern "C" void kernel_launch(void* const* d_in, const int* in_sizes, int n_in,
                              void* d_out, int out_size, void* d_ws, size_t ws_size,
                              hipStream_t stream) {
    const float* x     = (const float*)d_in[0];
    const int*   ei    = (const int*)d_in[1];
    const int*   batch = (const int*)d_in[2];
    const float* topo  = (const float*)d_in[3];
    const float* W1    = (const float*)d_in[4];
    const float* b1    = (const float*)d_in[5];
    const float* W2    = (const float*)d_in[6];
    const float* b2    = (const float*)d_in[7];
    const float* Wlin  = (const float*)d_in[8];
    const float* blin  = (const float*)d_in[9];
    float* out = (float*)d_out;

    const int N = in_sizes[0] / 64;      // 100000
    const int E = in_sizes[1] / 2;       // 1600000
    const int* src = ei;
    const int* dst = ei + E;
    const int nb2 = (N + 255) / 256;     // 391 dst-buckets of 256 nodes
    const int CE  = (E + NBLK - 1) / NBLK;

    // workspace layout (bytes)
    char* ws = (char*)d_ws;
    size_t off = 0;
    unsigned short* Abf = (unsigned short*)(ws + off); off += (size_t)N * 64 * 2;   // 12.8 MB (gemm1 bf16)
    unsigned* A8a    = (unsigned*)(ws + off); off += (size_t)N * 64;                // 6.4 MB (layer1 fp8)
    unsigned* A8b    = (unsigned*)(ws + off); off += (size_t)N * 64;                // 6.4 MB (layer2 fp8)
    int*      col    = (int*)     (ws + off); off += (size_t)E * 4;                 // 6.4 MB
    unsigned* ebuf   = (unsigned*)(ws + off); off += (size_t)E * 4;                 // 6.4 MB
    int*      bhist  = (int*)     (ws + off); off += (size_t)NBLK * nb2 * 4;        // 0.8 MB
    int*      ctot   = (int*)     (ws + off); off += (size_t)(nb2 + 8) * 4;
    int*      cbase  = (int*)     (ws + off); off += (size_t)(nb2 + 8) * 4;
    int*      rowptr = (int*)     (ws + off); off += (size_t)(N + 1) * 4;
    int*      degi   = (int*)     (ws + off); off += (size_t)N * 4;
    float*    dis    = (float*)   (ws + off); off += (size_t)N * 4;
    int*      gstart = (int*)     (ws + off); off += (size_t)(NGRAPH + 8) * 4;
    float*    gsum   = (float*)   (ws + off); off += (size_t)NGRAPH * 64 * 4;

    // zero pool accumulators (ws is poisoned with 0xAA every call)
    hipMemsetAsync(gsum, 0, (size_t)NGRAPH * 64 * 4, stream);

    // ---- build: gemm1+histogram -> column scan -> (base scan | gstart) -> scatter -> CSR -----
    const int nWaves = (N + GROWS - 1) / GROWS;  // 12500
    const int Gg = (nWaves + 3) / 4;             // 3125 gemm blocks
    hybrid_gemm_hist_kernel<<<Gg + NBLK, 256, 0, stream>>>(x, W1, Abf, dst, bhist, N, E, Gg, nb2, CE);
    scan_cols_kernel<<<nb2, 256, 0, stream>>>(bhist, ctot, nb2);
    scan_gstart_kernel<<<2, 256, 0, stream>>>(ctot, cbase, batch, gstart, nb2, N);
    scatter_sorted_kernel<<<NBLK, 256, 0, stream>>>(src, dst, bhist, cbase, ebuf, E, nb2, CE);
    build_csr_kernel<<<nb2, 256, 0, stream>>>(ebuf, cbase, col, rowptr, degi, dis,
                                              (const unsigned*)Abf, A8a, N);

    // ---- layer 1 pull + GEMM2 fused (no Bbf round trip) ----
    int pullBlocks = ((N + 7) / 8 + 3) / 4;      // 3125
    pull1_gemm_kernel<<<pullBlocks, 256, 0, stream>>>(A8a, rowptr, degi, dis, b1, col, W2, A8b, N);

    // ---- layer 2 pull + mean-pool fused (no B2 round trip, no pool kernel) ----
    pull2_pool_kernel<<<pullBlocks, 256, 0, stream>>>(A8b, rowptr, degi, dis, b2, col,
                                                      batch, gsum, N);

    // ---- head ----
    head_kernel<<<1, 256, 0, stream>>>(gsum, gstart, topo, Wlin, blin, out);
}